// Round 2
// baseline (236.890 us; speedup 1.0000x reference)
//
#include <hip/hip_runtime.h>
#include <hip/hip_bf16.h>
#include <stdint.h>

#define B_ 128
#define N_ 512
#define I_ 256
#define M_ 32
#define D_ 16

typedef __attribute__((ext_vector_type(4))) float f32x4;
typedef __attribute__((ext_vector_type(4))) float float4v;
typedef __attribute__((ext_vector_type(8))) short short8;   // 8 bf16 (4 VGPRs) — MFMA A/B frag
typedef __attribute__((ext_vector_type(4))) unsigned short ushort4v;

__device__ __forceinline__ float bf2f(unsigned short u) {
    union { unsigned int i; float f; } v; v.i = ((unsigned int)u) << 16; return v.f;
}
__device__ __forceinline__ unsigned short f2bf(float f) {
    union { float f; unsigned int i; } v; v.f = f;
    unsigned int r = v.i + 0x7FFFu + ((v.i >> 16) & 1u);   // RNE
    return (unsigned short)(r >> 16);
}

// -----------------------------------------------------------------------------
// Kernel 1: inputs_hat[b,m,n,d] = sum_i x[b,n,i] * W[m,n,d,i]   (bf16 MFMA)
// Per block: one n, one chunk of 128 (m,d)-columns, all 128 b-rows.
// Tile 128x128, BK=64, 4 waves each owning a 32-row band (2x8 16x16 MFMA tiles).
// -----------------------------------------------------------------------------
#define LDK 72   // 64 + 8 pad: rotates bank start by 4/row, keeps 16B alignment

__global__ __launch_bounds__(256) void hat_gemm(const float* __restrict__ x,
                                                const float* __restrict__ W,
                                                unsigned short* __restrict__ hat) {
    __shared__ unsigned short As[128][LDK];   // [b_local][k]
    __shared__ unsigned short Bs[128][LDK];   // [col_local][k], col = m_local*16 + d

    const int n    = blockIdx.y;
    const int mc   = blockIdx.x;        // 0..3 -> cols [mc*128, mc*128+128)
    const int tid  = threadIdx.x;
    const int lane = tid & 63;
    const int w    = tid >> 6;          // wave 0..3 -> rows [w*32, w*32+32)

    // staging assignment: thread t stages row (t>>1), half (t&1) of 64 k's
    const int srow  = tid >> 1;         // 0..127
    const int shalf = tid & 1;

    const int   bm   = mc * 8 + (srow >> 4);   // global m for B staging
    const int   bd   = srow & 15;              // d for B staging
    const float* xrow = x + ((size_t)srow * N_ + n) * I_ + shalf * 32;
    const float* wrow = W + (((size_t)bm * N_ + n) * D_ + bd) * I_ + shalf * 32;

    f32x4 acc[2][8];
    #pragma unroll
    for (int a = 0; a < 2; ++a)
        #pragma unroll
        for (int c = 0; c < 8; ++c) { f32x4 z = {0.f, 0.f, 0.f, 0.f}; acc[a][c] = z; }

    for (int k0 = 0; k0 < I_; k0 += 64) {
        // ---- stage fp32 -> bf16 into LDS ----
        #pragma unroll
        for (int j = 0; j < 8; ++j) {
            float4v va = *(const float4v*)(xrow + k0 + j * 4);
            float4v vb = *(const float4v*)(wrow + k0 + j * 4);
            ushort4v ha, hb;
            ha[0] = f2bf(va[0]); ha[1] = f2bf(va[1]); ha[2] = f2bf(va[2]); ha[3] = f2bf(va[3]);
            hb[0] = f2bf(vb[0]); hb[1] = f2bf(vb[1]); hb[2] = f2bf(vb[2]); hb[3] = f2bf(vb[3]);
            *(ushort4v*)&As[srow][shalf * 32 + j * 4] = ha;
            *(ushort4v*)&Bs[srow][shalf * 32 + j * 4] = hb;
        }
        __syncthreads();
        // ---- MFMA on the staged BK=64 slice (two K=32 steps) ----
        #pragma unroll
        for (int ks = 0; ks < 2; ++ks) {
            const int kb = ks * 32 + ((lane >> 4) << 3);
            // A frag: row = lane&15 (+tile), k = (lane>>4)*8 + j
            short8 a0 = *(const short8*)&As[w * 32 +      (lane & 15)][kb];
            short8 a1 = *(const short8*)&As[w * 32 + 16 + (lane & 15)][kb];
            #pragma unroll
            for (int ct = 0; ct < 8; ++ct) {
                // B frag: col = lane&15 (+tile), k = (lane>>4)*8 + j
                short8 bb = *(const short8*)&Bs[ct * 16 + (lane & 15)][kb];
                acc[0][ct] = __builtin_amdgcn_mfma_f32_16x16x32_bf16(a0, bb, acc[0][ct], 0, 0, 0);
                acc[1][ct] = __builtin_amdgcn_mfma_f32_16x16x32_bf16(a1, bb, acc[1][ct], 0, 0, 0);
            }
        }
        __syncthreads();
    }

    // ---- epilogue: D lane map (verified): col = lane&15, row = (lane>>4)*4 + r ----
    const int d  = lane & 15;
    const int rq = lane >> 4;
    #pragma unroll
    for (int rt = 0; rt < 2; ++rt) {
        #pragma unroll
        for (int ct = 0; ct < 8; ++ct) {
            const int m = mc * 8 + ct;
            #pragma unroll
            for (int r = 0; r < 4; ++r) {
                const int brow = w * 32 + rt * 16 + rq * 4 + r;
                const size_t idx = (((size_t)brow * M_ + m) * N_ + n) * D_ + d;
                hat[idx] = f2bf(acc[rt][ct][r]);
            }
        }
    }
}

// -----------------------------------------------------------------------------
// Kernel 2: dynamic routing (3 iterations), one block per batch element b.
// 8 waves; wave w owns m in [w*4, w*4+4). b-logits [32][512] fp32 live in LDS.
// Output d_out is FLOAT32 (reference returns jnp.float32).
// -----------------------------------------------------------------------------
__global__ __launch_bounds__(512) void routing(const unsigned short* __restrict__ hat,
                                               float* __restrict__ out) {
    __shared__ float blog[M_][N_];     // 64 KB
    __shared__ float cmax[N_];         // softmax col max  (over m)
    __shared__ float rcsum[N_];        // 1 / softmax col sum

    const int b    = blockIdx.x;
    const int tid  = threadIdx.x;      // 0..511
    const int lane = tid & 63;
    const int w    = tid >> 6;         // 0..7

    #pragma unroll
    for (int m = 0; m < M_; ++m) blog[m][tid] = 0.f;
    __syncthreads();

    float ov[4][16];                   // squash output for this wave's 4 m's

    for (int it = 0; it < 3; ++it) {
        // ---- phase A: per-n softmax stats over m (thread t handles n = t) ----
        {
            float mx = -3.4e38f;
            #pragma unroll
            for (int m = 0; m < M_; ++m) mx = fmaxf(mx, blog[m][tid]);
            float s = 0.f;
            #pragma unroll
            for (int m = 0; m < M_; ++m) s += __expf(blog[m][tid] - mx);
            cmax[tid]  = mx;
            rcsum[tid] = 1.f / s;
        }
        __syncthreads();

        // ---- phase B: s[m,d] = sum_n c[m,n]*hat[b,m,n,d], then squash ----
        float sacc[4][16];
        #pragma unroll
        for (int q = 0; q < 4; ++q)
            #pragma unroll
            for (int dd = 0; dd < 16; ++dd) sacc[q][dd] = 0.f;

        for (int r = 0; r < 8; ++r) {
            const int nn = r * 64 + lane;
            #pragma unroll
            for (int q = 0; q < 4; ++q) {
                const int m = w * 4 + q;
                const float cm = __expf(blog[m][nn] - cmax[nn]) * rcsum[nn];
                const size_t base = (((size_t)b * M_ + m) * N_ + nn) * D_;
                short8 h0 = *(const short8*)(hat + base);
                short8 h1 = *(const short8*)(hat + base + 8);
                #pragma unroll
                for (int dd = 0; dd < 8; ++dd) {
                    sacc[q][dd]     += cm * bf2f((unsigned short)h0[dd]);
                    sacc[q][8 + dd] += cm * bf2f((unsigned short)h1[dd]);
                }
            }
        }
        // cross-lane reduce (butterfly over 64 lanes)
        #pragma unroll
        for (int off = 32; off >= 1; off >>= 1) {
            #pragma unroll
            for (int q = 0; q < 4; ++q)
                #pragma unroll
                for (int dd = 0; dd < 16; ++dd)
                    sacc[q][dd] += __shfl_xor(sacc[q][dd], off, 64);
        }
        // squash
        #pragma unroll
        for (int q = 0; q < 4; ++q) {
            float s2 = 0.f;
            #pragma unroll
            for (int dd = 0; dd < 16; ++dd) s2 += sacc[q][dd] * sacc[q][dd];
            const float scale = s2 / (1.f + s2) / sqrtf(s2 + 1e-7f);
            #pragma unroll
            for (int dd = 0; dd < 16; ++dd) ov[q][dd] = scale * sacc[q][dd];
        }

        // ---- phase C: b[m,n] += sum_d out[m,d]*hat[b,m,n,d]  (iters 0,1) ----
        if (it < 2) {
            for (int r = 0; r < 8; ++r) {
                const int nn = r * 64 + lane;
                #pragma unroll
                for (int q = 0; q < 4; ++q) {
                    const int m = w * 4 + q;
                    const size_t base = (((size_t)b * M_ + m) * N_ + nn) * D_;
                    short8 h0 = *(const short8*)(hat + base);
                    short8 h1 = *(const short8*)(hat + base + 8);
                    float dot = 0.f;
                    #pragma unroll
                    for (int dd = 0; dd < 8; ++dd) {
                        dot += ov[q][dd]     * bf2f((unsigned short)h0[dd]);
                        dot += ov[q][8 + dd] * bf2f((unsigned short)h1[dd]);
                    }
                    blog[m][nn] += dot;
                }
            }
        }
        __syncthreads();
    }

    // ---- write final outputs [B, M, D] as FP32 ----
    if (lane == 0) {
        #pragma unroll
        for (int q = 0; q < 4; ++q) {
            const int m = w * 4 + q;
            #pragma unroll
            for (int c4 = 0; c4 < 4; ++c4) {
                float4v v;
                v[0] = ov[q][c4 * 4 + 0];
                v[1] = ov[q][c4 * 4 + 1];
                v[2] = ov[q][c4 * 4 + 2];
                v[3] = ov[q][c4 * 4 + 3];
                *(float4v*)&out[((size_t)b * M_ + m) * D_ + c4 * 4] = v;
            }
        }
    }
}

extern "C" void kernel_launch(void* const* d_in, const int* in_sizes, int n_in,
                              void* d_out, int out_size, void* d_ws, size_t ws_size,
                              hipStream_t stream) {
    const float* x = (const float*)d_in[0];   // [128, 512, 256] fp32
    const float* W = (const float*)d_in[1];   // [32, 512, 16, 256] fp32
    unsigned short* hat = (unsigned short*)d_ws;   // bf16 [128,32,512,16] = 64 MB scratch
    float* out = (float*)d_out;                    // fp32 [128,32,16]

    dim3 g1(4, N_);
    hat_gemm<<<g1, dim3(256), 0, stream>>>(x, W, hat);
    routing<<<dim3(B_), dim3(512), 0, stream>>>(hat, out);
}

// Round 3
// 190.377 us; speedup vs baseline: 1.2443x; 1.2443x over previous
//
#include <hip/hip_runtime.h>
#include <hip/hip_bf16.h>
#include <stdint.h>

#define B_ 128
#define N_ 512
#define I_ 256
#define M_ 32
#define D_ 16

typedef __attribute__((ext_vector_type(4))) float f32x4;
typedef __attribute__((ext_vector_type(4))) float float4v;
typedef __attribute__((ext_vector_type(8))) short short8;   // 8 bf16 (4 VGPRs) — MFMA A/B frag
typedef __attribute__((ext_vector_type(4))) unsigned short ushort4v;

__device__ __forceinline__ float bf2f(unsigned short u) {
    union { unsigned int i; float f; } v; v.i = ((unsigned int)u) << 16; return v.f;
}
__device__ __forceinline__ unsigned short f2bf(float f) {
    union { float f; unsigned int i; } v; v.f = f;
    unsigned int r = v.i + 0x7FFFu + ((v.i >> 16) & 1u);   // RNE
    return (unsigned short)(r >> 16);
}

// -----------------------------------------------------------------------------
// Kernel 1: inputs_hat[b,m,n,d] = sum_i x[b,n,i] * W[m,n,d,i]   (bf16 MFMA)
// Per block: one n, 128 (m,d)-cols (mc*8..+8 m's), all 128 b-rows. BK=64.
// Staging v2: 16-lane x 256B contiguous segments (row = r*16 + tid>>4,
// k = (tid&15)*4), issue-early prefetch of tile k+1 across MFMA of tile k.
// -----------------------------------------------------------------------------
#define LDK 72   // 64 + 8 pad

__global__ __launch_bounds__(256) void hat_gemm(const float* __restrict__ x,
                                                const float* __restrict__ W,
                                                unsigned short* __restrict__ hat) {
    __shared__ unsigned short As[128][LDK];   // [b_local][k]
    __shared__ unsigned short Bs[128][LDK];   // [col_local][k], col = m_local*16 + d

    const int n    = blockIdx.y;
    const int mc   = blockIdx.x;        // 0..3 -> m in [mc*8, mc*8+8)
    const int tid  = threadIdx.x;
    const int lane = tid & 63;
    const int w    = tid >> 6;          // wave 0..3 -> rows [w*32, w*32+32)

    // staging: round r in 0..7 covers rows/cols [r*16, r*16+16)
    const int sgrp  = tid >> 4;         // 0..15  row-within-round
    const int klane = (tid & 15) * 4;   // k offset, 16 lanes * float4 = 256 B contiguous

    // A row (b = r*16+sgrp):  x[(row*N + n)*I + k]
    const float* xbase = x + ((size_t)sgrp * N_ + n) * I_ + klane;
    // B col (c = r*16+sgrp -> m = mc*8 + r, d = sgrp): W[((m*N + n)*D + d)*I + k]
    const float* wbase = W + (((size_t)(mc * 8) * N_ + n) * D_ + sgrp) * I_ + klane;

    const size_t xstep = (size_t)16 * N_ * I_;   // row += 16
    const size_t wstep = (size_t)N_ * D_ * I_;   // m += 1

    float4v pa[8], pb[8];

    f32x4 acc[2][8];
    #pragma unroll
    for (int a = 0; a < 2; ++a)
        #pragma unroll
        for (int c = 0; c < 8; ++c) { f32x4 z = {0.f, 0.f, 0.f, 0.f}; acc[a][c] = z; }

    // prologue: issue loads for k-tile 0
    #pragma unroll
    for (int r = 0; r < 8; ++r) {
        pa[r] = *(const float4v*)(xbase + (size_t)r * xstep);
        pb[r] = *(const float4v*)(wbase + (size_t)r * wstep);
    }

    for (int kt = 0; kt < 4; ++kt) {
        // ---- convert + write LDS (waits on in-flight loads) ----
        #pragma unroll
        for (int r = 0; r < 8; ++r) {
            ushort4v ha, hb;
            ha[0] = f2bf(pa[r][0]); ha[1] = f2bf(pa[r][1]);
            ha[2] = f2bf(pa[r][2]); ha[3] = f2bf(pa[r][3]);
            hb[0] = f2bf(pb[r][0]); hb[1] = f2bf(pb[r][1]);
            hb[2] = f2bf(pb[r][2]); hb[3] = f2bf(pb[r][3]);
            *(ushort4v*)&As[r * 16 + sgrp][klane] = ha;
            *(ushort4v*)&Bs[r * 16 + sgrp][klane] = hb;
        }
        __syncthreads();

        // ---- issue loads for k-tile kt+1 (in flight across MFMA) ----
        if (kt < 3) {
            const int k0 = (kt + 1) * 64;
            #pragma unroll
            for (int r = 0; r < 8; ++r) {
                pa[r] = *(const float4v*)(xbase + (size_t)r * xstep + k0);
                pb[r] = *(const float4v*)(wbase + (size_t)r * wstep + k0);
            }
        }

        // ---- MFMA on the staged BK=64 slice (two K=32 steps) ----
        #pragma unroll
        for (int ks = 0; ks < 2; ++ks) {
            const int kb = ks * 32 + ((lane >> 4) << 3);
            short8 a0 = *(const short8*)&As[w * 32 +      (lane & 15)][kb];
            short8 a1 = *(const short8*)&As[w * 32 + 16 + (lane & 15)][kb];
            #pragma unroll
            for (int ct = 0; ct < 8; ++ct) {
                short8 bb = *(const short8*)&Bs[ct * 16 + (lane & 15)][kb];
                acc[0][ct] = __builtin_amdgcn_mfma_f32_16x16x32_bf16(a0, bb, acc[0][ct], 0, 0, 0);
                acc[1][ct] = __builtin_amdgcn_mfma_f32_16x16x32_bf16(a1, bb, acc[1][ct], 0, 0, 0);
            }
        }
        __syncthreads();
    }

    // ---- epilogue: D lane map: col = lane&15, row = (lane>>4)*4 + r ----
    const int d  = lane & 15;
    const int rq = lane >> 4;
    #pragma unroll
    for (int rt = 0; rt < 2; ++rt) {
        #pragma unroll
        for (int ct = 0; ct < 8; ++ct) {
            const int m = mc * 8 + ct;
            #pragma unroll
            for (int r = 0; r < 4; ++r) {
                const int brow = w * 32 + rt * 16 + rq * 4 + r;
                const size_t idx = (((size_t)brow * M_ + m) * N_ + n) * D_ + d;
                hat[idx] = f2bf(acc[rt][ct][r]);
            }
        }
    }
}

// -----------------------------------------------------------------------------
// Kernel 2: dynamic routing (3 iterations), one block per batch element b.
// 8 waves; wave w owns m in [w*4, w*4+4). b-logits [32][512] fp32 live in LDS.
// Output d_out is FLOAT32.
// -----------------------------------------------------------------------------
__global__ __launch_bounds__(512) void routing(const unsigned short* __restrict__ hat,
                                               float* __restrict__ out) {
    __shared__ float blog[M_][N_];     // 64 KB
    __shared__ float cmax[N_];
    __shared__ float rcsum[N_];

    const int b    = blockIdx.x;
    const int tid  = threadIdx.x;      // 0..511
    const int lane = tid & 63;
    const int w    = tid >> 6;         // 0..7

    #pragma unroll
    for (int m = 0; m < M_; ++m) blog[m][tid] = 0.f;
    __syncthreads();

    float ov[4][16];

    for (int it = 0; it < 3; ++it) {
        // ---- phase A: per-n softmax stats over m ----
        {
            float mx = -3.4e38f;
            #pragma unroll
            for (int m = 0; m < M_; ++m) mx = fmaxf(mx, blog[m][tid]);
            float s = 0.f;
            #pragma unroll
            for (int m = 0; m < M_; ++m) s += __expf(blog[m][tid] - mx);
            cmax[tid]  = mx;
            rcsum[tid] = 1.f / s;
        }
        __syncthreads();

        // ---- phase B: s[m,d] = sum_n c[m,n]*hat[b,m,n,d], then squash ----
        float sacc[4][16];
        #pragma unroll
        for (int q = 0; q < 4; ++q)
            #pragma unroll
            for (int dd = 0; dd < 16; ++dd) sacc[q][dd] = 0.f;

        for (int r = 0; r < 8; ++r) {
            const int nn = r * 64 + lane;
            #pragma unroll
            for (int q = 0; q < 4; ++q) {
                const int m = w * 4 + q;
                const float cm = __expf(blog[m][nn] - cmax[nn]) * rcsum[nn];
                const size_t base = (((size_t)b * M_ + m) * N_ + nn) * D_;
                short8 h0 = *(const short8*)(hat + base);
                short8 h1 = *(const short8*)(hat + base + 8);
                #pragma unroll
                for (int dd = 0; dd < 8; ++dd) {
                    sacc[q][dd]     += cm * bf2f((unsigned short)h0[dd]);
                    sacc[q][8 + dd] += cm * bf2f((unsigned short)h1[dd]);
                }
            }
        }
        #pragma unroll
        for (int off = 32; off >= 1; off >>= 1) {
            #pragma unroll
            for (int q = 0; q < 4; ++q)
                #pragma unroll
                for (int dd = 0; dd < 16; ++dd)
                    sacc[q][dd] += __shfl_xor(sacc[q][dd], off, 64);
        }
        #pragma unroll
        for (int q = 0; q < 4; ++q) {
            float s2 = 0.f;
            #pragma unroll
            for (int dd = 0; dd < 16; ++dd) s2 += sacc[q][dd] * sacc[q][dd];
            const float scale = s2 / (1.f + s2) / sqrtf(s2 + 1e-7f);
            #pragma unroll
            for (int dd = 0; dd < 16; ++dd) ov[q][dd] = scale * sacc[q][dd];
        }

        // ---- phase C: b[m,n] += sum_d out[m,d]*hat[b,m,n,d]  (iters 0,1) ----
        if (it < 2) {
            for (int r = 0; r < 8; ++r) {
                const int nn = r * 64 + lane;
                #pragma unroll
                for (int q = 0; q < 4; ++q) {
                    const int m = w * 4 + q;
                    const size_t base = (((size_t)b * M_ + m) * N_ + nn) * D_;
                    short8 h0 = *(const short8*)(hat + base);
                    short8 h1 = *(const short8*)(hat + base + 8);
                    float dot = 0.f;
                    #pragma unroll
                    for (int dd = 0; dd < 8; ++dd) {
                        dot += ov[q][dd]     * bf2f((unsigned short)h0[dd]);
                        dot += ov[q][8 + dd] * bf2f((unsigned short)h1[dd]);
                    }
                    blog[m][nn] += dot;
                }
            }
        }
        __syncthreads();
    }

    // ---- write final outputs [B, M, D] as FP32 ----
    if (lane == 0) {
        #pragma unroll
        for (int q = 0; q < 4; ++q) {
            const int m = w * 4 + q;
            #pragma unroll
            for (int c4 = 0; c4 < 4; ++c4) {
                float4v v;
                v[0] = ov[q][c4 * 4 + 0];
                v[1] = ov[q][c4 * 4 + 1];
                v[2] = ov[q][c4 * 4 + 2];
                v[3] = ov[q][c4 * 4 + 3];
                *(float4v*)&out[((size_t)b * M_ + m) * D_ + c4 * 4] = v;
            }
        }
    }
}

extern "C" void kernel_launch(void* const* d_in, const int* in_sizes, int n_in,
                              void* d_out, int out_size, void* d_ws, size_t ws_size,
                              hipStream_t stream) {
    const float* x = (const float*)d_in[0];   // [128, 512, 256] fp32
    const float* W = (const float*)d_in[1];   // [32, 512, 16, 256] fp32
    unsigned short* hat = (unsigned short*)d_ws;   // bf16 [128,32,512,16] = 64 MB scratch
    float* out = (float*)d_out;                    // fp32 [128,32,16]

    dim3 g1(4, N_);
    hat_gemm<<<g1, dim3(256), 0, stream>>>(x, W, hat);
    routing<<<dim3(B_), dim3(512), 0, stream>>>(hat, out);
}